// Round 6
// baseline (692.053 us; speedup 1.0000x reference)
//
#include <hip/hip_runtime.h>
#include <stdint.h>

// ---------------------------------------------------------------------------
// Ternary 3x3 conv block via i8 MFMA implicit GEMM, register double-buffered.
//
// Activations: NHWC i8 ternary {-1,0,+1}, padded [64][58][58][256], halo = 0
//   (halos of BOTH buffers zeroed inside pack_x_kernel).
// Weights pre-packed in MFMA B-fragment order:
//   Bpk[nfrag(16)][unit(36)][lane(64)][16B], unit = tap*4 + cich.
// mconv block: M=112 (2 out rows) x N=256 x K=2304, 4 waves (N-split 64 each).
//   4 input rows staged in LDS (63.1 KB, PPIX=272: balanced banks).
//   K-loop fully unrolled over 36 units with A(LDS) and B(global) register
//   double-buffers: loads for unit u+1 issue before the 28 MFMAs of unit u,
//   so ds/vm waits land under ~570 cyc of matrix work.
// C/D layout: col=lane&15, row=(lane>>4)*4+reg (verified absmax 0).
// ---------------------------------------------------------------------------

#define NB 64
#define C  256
#define H  56
#define W  56
#define HP 58
#define PPIX 272                 // padded bytes per pixel in LDS (17*16)
#define SLOT (HP * PPIX)         // bytes per LDS row slot
#define OST 272                  // transpose row stride (256+16)

typedef int v4i __attribute__((ext_vector_type(4)));

// ---- pack input NCHW fp32 -> padded NHWC ternary i8; zero halos of Aq & Bq -
__global__ __launch_bounds__(256)
void pack_x_kernel(const float* __restrict__ x, int8_t* __restrict__ Aq,
                   int8_t* __restrict__ Bq) {
    const int hp = blockIdx.x;       // padded row 0..57
    const int n  = blockIdx.y;
    const int tid = threadIdx.x;
    int8_t* arow = Aq + ((size_t)n * HP + hp) * HP * C;
    int8_t* brow = Bq + ((size_t)n * HP + hp) * HP * C;
    const v4i z = (v4i){0, 0, 0, 0};

    if (hp == 0 || hp == HP - 1) {   // full top/bottom halo rows
        for (int idx = tid; idx < HP * 16; idx += 256) {
            *(v4i*)(arow + (size_t)idx * 16) = z;
            *(v4i*)(brow + (size_t)idx * 16) = z;
        }
        return;
    }
    // left/right halo pixels of this row, both buffers (64 chunks)
    if (tid < 64) {
        int buf = tid >> 5, px = (tid >> 4) & 1, c16 = tid & 15;
        int8_t* p = (buf ? brow : arow) + (size_t)(px ? (HP - 1) : 0) * C + c16 * 16;
        *(v4i*)p = z;
    }

    const int w  = tid & 63;   // 0..55 valid
    const int cq = tid >> 6;   // 64-channel group
    __shared__ int8_t st[56 * OST];
    const float* xp = x + (((size_t)n * C + cq * 64) * H + (hp - 1)) * W + w;
#pragma unroll
    for (int i = 0; i < 16; ++i) {
        uint32_t u = 0;
#pragma unroll
        for (int b = 0; b < 4; ++b) {
            float v = (w < 56) ? xp[(size_t)(i * 4 + b) * (H * W)] : 0.0f;
            uint32_t t = (v < 0.0f) ? 0xFFu : ((v != 0.0f) ? 1u : 0u);
            u |= t << (8 * b);
        }
        if (w < 56)
            *(uint32_t*)(st + w * OST + cq * 64 + i * 4) = u;
    }
    __syncthreads();
    int8_t* dst = arow + C;          // col 1
    for (int idx = tid; idx < 56 * 16; idx += 256) {
        int pix = idx >> 4, c16 = idx & 15;
        *(v4i*)(dst + (size_t)pix * C + c16 * 16) =
            *(const v4i*)(st + pix * OST + c16 * 16);
    }
}

// ---- pack weights into B-fragment order -----------------------------------
__global__ __launch_bounds__(64)
void pack_w_kernel(const float* __restrict__ wa, const float* __restrict__ wb,
                   int8_t* __restrict__ B1, int8_t* __restrict__ B2) {
    const int kstep = blockIdx.x;   // 0..35
    const int nfrag = blockIdx.y;   // 0..15
    const float* wsrc = blockIdx.z ? wb : wa;
    int8_t* dst       = blockIdx.z ? B2 : B1;
    const int lane = threadIdx.x, quad = lane >> 4, l16 = lane & 15;
    const int co = nfrag * 16 + l16;
    uint32_t pk[4];
#pragma unroll
    for (int d = 0; d < 4; ++d) {
        uint32_t u = 0;
#pragma unroll
        for (int bb = 0; bb < 4; ++bb) {
            int k = kstep * 64 + quad * 16 + d * 4 + bb;
            int tap = k >> 8, ci = k & 255;
            float v = wsrc[((size_t)co * C + ci) * 9 + tap];
            uint32_t t = (v < 0.0f) ? 0xFFu : ((v != 0.0f) ? 1u : 0u);
            u |= t << (8 * bb);
        }
        pk[d] = u;
    }
    uint4 st; st.x = pk[0]; st.y = pk[1]; st.z = pk[2]; st.w = pk[3];
    *(uint4*)(dst + ((size_t)(nfrag * 36 + kstep) * 64 + lane) * 16) = st;
}

// ---- the conv kernels ------------------------------------------------------
// STAGE 1: GEMM -> BN -> ternarize -> LDS transpose -> coalesced NHWC i8.
// STAGE 2: GEMM -> BN -> +residual -> clip -> fp32 NCHW (float4).
template <int STAGE>
__global__ __launch_bounds__(256, 2)
void mconv_kernel(const int8_t* __restrict__ Aq, const int8_t* __restrict__ Bpk,
                  const float* __restrict__ gamma, const float* __restrict__ beta,
                  const float* __restrict__ mean,  const float* __restrict__ var,
                  const float* __restrict__ resid,
                  int8_t* __restrict__ Bout, float* __restrict__ out) {
    const int h2 = blockIdx.x;   // output rows h2*2, h2*2+1
    const int n  = blockIdx.y;
    const int tid = threadIdx.x;
    const int wv = tid >> 6, lane = tid & 63, quad = lane >> 4, l16 = lane & 15;

    __shared__ int8_t lds[4 * SLOT];   // 63104 B

    const int8_t* gA = Aq + ((size_t)n * HP + h2 * 2) * HP * C;
    for (int idx = tid; idx < 4 * HP * 16; idx += 256) {
        int pix = idx >> 4, c16 = idx & 15;
        *(v4i*)(lds + pix * PPIX + c16 * 16) =
            *(const v4i*)(gA + (size_t)pix * C + c16 * 16);
    }
    __syncthreads();

    int abase[7];
#pragma unroll
    for (int f = 0; f < 7; ++f) {
        int mm = f * 16 + l16;
        int hl = (mm >= 56) ? 1 : 0;
        int w  = mm - 56 * hl;
        abase[f] = hl * SLOT + w * PPIX + quad * 16;
    }

    const int8_t* bq[4];
#pragma unroll
    for (int nf = 0; nf < 4; ++nf)
        bq[nf] = Bpk + (size_t)((wv * 4 + nf) * 36) * 1024 + lane * 16;

    v4i acc[7][4];
#pragma unroll
    for (int f = 0; f < 7; ++f)
#pragma unroll
        for (int nf = 0; nf < 4; ++nf) acc[f][nf] = (v4i){0, 0, 0, 0};

    // register double-buffers
    v4i aA[7], aB[7], bA[4], bB[4];
#pragma unroll
    for (int f = 0; f < 7; ++f) aA[f] = *(const v4i*)(lds + abase[f]);   // unit 0: au=0
#pragma unroll
    for (int nf = 0; nf < 4; ++nf) bA[nf] = *(const v4i*)(bq[nf]);

#pragma unroll
    for (int u = 0; u < 36; ++u) {
        const int un = u + 1;
        const int tn = un >> 2, cin = un & 3;
        const int rn = tn / 3, cn = tn - 3 * rn;
        const int aun = (un < 36) ? (rn * SLOT + cn * PPIX + cin * 64) : 0;
        v4i* ac  = (u & 1) ? aB : aA;
        v4i* an  = (u & 1) ? aA : aB;
        v4i* bc  = (u & 1) ? bB : bA;
        v4i* bn_ = (u & 1) ? bA : bB;
#pragma unroll
        for (int f = 0; f < 7; ++f)
            an[f] = *(const v4i*)(lds + abase[f] + aun);
#pragma unroll
        for (int nf = 0; nf < 4; ++nf)
            bn_[nf] = *(const v4i*)(bq[nf] + (size_t)un * 1024);
#pragma unroll
        for (int f = 0; f < 7; ++f)
#pragma unroll
            for (int nf = 0; nf < 4; ++nf)
                acc[f][nf] = __builtin_amdgcn_mfma_i32_16x16x64_i8(
                    ac[f], bc[nf], acc[f][nf], 0, 0, 0);
    }

    // ---- epilogue ----
    if (STAGE == 1) {
        __syncthreads();   // K-loop LDS dead; reuse as transpose buffer
#pragma unroll
        for (int nf = 0; nf < 4; ++nf) {
            const int co = (wv * 4 + nf) * 16 + l16;
            double scd = (double)gamma[co] / sqrt((double)var[co] + 1e-5);
            float scale = (float)scd;
            float shift = (float)((double)beta[co] - (double)mean[co] * scd);
#pragma unroll
            for (int f = 0; f < 7; ++f) {
#pragma unroll
                for (int reg = 0; reg < 4; ++reg) {
                    int mm = f * 16 + quad * 4 + reg;
                    float v = __fadd_rn(__fmul_rn((float)acc[f][nf][reg], scale), shift);
                    int8_t t8 = (v < 0.0f) ? (int8_t)-1
                              : ((v != 0.0f) ? (int8_t)1 : (int8_t)0);
                    lds[mm * OST + co] = t8;
                }
            }
        }
        __syncthreads();
        for (int idx = tid; idx < 112 * 16; idx += 256) {
            int mm = idx >> 4, c16 = idx & 15;
            int hl = (mm >= 56) ? 1 : 0;
            int ww = mm - 56 * hl;
            int oh = h2 * 2 + hl;
            *(v4i*)(Bout + (((size_t)n * HP + oh + 1) * HP + ww + 1) * C + c16 * 16)
                = *(const v4i*)(lds + mm * OST + c16 * 16);
        }
    } else {
#pragma unroll
        for (int nf = 0; nf < 4; ++nf) {
            const int co = (wv * 4 + nf) * 16 + l16;
            double scd = (double)gamma[co] / sqrt((double)var[co] + 1e-5);
            float scale = (float)scd;
            float shift = (float)((double)beta[co] - (double)mean[co] * scd);
#pragma unroll
            for (int f = 0; f < 7; ++f) {
                int mmb = f * 16 + quad * 4;   // 4-aligned: row uniform over reg
                int hl = (mmb >= 56) ? 1 : 0;
                int w0 = mmb - 56 * hl;
                int oh = h2 * 2 + hl;
                size_t ridx = (((size_t)n * C + co) * H + oh) * W + w0;
                float4 rv = *(const float4*)(resid + ridx);
                float rr[4] = {rv.x, rv.y, rv.z, rv.w};
                float oo[4];
#pragma unroll
                for (int reg = 0; reg < 4; ++reg) {
                    float v = __fadd_rn(__fmul_rn((float)acc[f][nf][reg], scale), shift);
                    float o = v + rr[reg];
                    oo[reg] = fminf(1.0f, fmaxf(-1.0f, o));
                }
                float4 ov; ov.x = oo[0]; ov.y = oo[1]; ov.z = oo[2]; ov.w = oo[3];
                *(float4*)(out + ridx) = ov;
            }
        }
    }
}

extern "C" void kernel_launch(void* const* d_in, const int* in_sizes, int n_in,
                              void* d_out, int out_size, void* d_ws, size_t ws_size,
                              hipStream_t stream) {
    const float* x  = (const float*)d_in[0];
    const float* w1 = (const float*)d_in[1];
    const float* g1 = (const float*)d_in[2];
    const float* b1 = (const float*)d_in[3];
    const float* m1 = (const float*)d_in[4];
    const float* v1 = (const float*)d_in[5];
    const float* w2 = (const float*)d_in[6];
    const float* g2 = (const float*)d_in[7];
    const float* b2 = (const float*)d_in[8];
    const float* m2 = (const float*)d_in[9];
    const float* v2 = (const float*)d_in[10];
    float* out = (float*)d_out;

    uint8_t* ws = (uint8_t*)d_ws;
    const size_t ASZ = (size_t)NB * HP * HP * C;       // 55,083,008 B per act buffer
    const size_t WPK = (size_t)16 * 36 * 64 * 16;      // 589,824 B per packed weight
    int8_t* Aq   = (int8_t*)(ws);
    int8_t* Bq   = (int8_t*)(ws + ASZ);
    int8_t* Bpk1 = (int8_t*)(ws + 2 * ASZ);
    int8_t* Bpk2 = (int8_t*)(ws + 2 * ASZ + WPK);
    // note: mconv's B-prefetch reads up to 1 KB past each nfrag block; the
    // last read lands in [Bpk2+WPK, Bpk2+WPK+1KB) which stays inside d_ws
    // (same footprint as R5, which passed).

    pack_w_kernel<<<dim3(36, 16, 2), 64, 0, stream>>>(w1, w2, Bpk1, Bpk2);
    pack_x_kernel<<<dim3(HP, NB), 256, 0, stream>>>(x, Aq, Bq);
    mconv_kernel<1><<<dim3(28, NB), 256, 0, stream>>>(Aq, Bpk1, g1, b1, m1, v1,
                                                      nullptr, Bq, nullptr);
    mconv_kernel<2><<<dim3(28, NB), 256, 0, stream>>>(Bq, Bpk2, g2, b2, m2, v2,
                                                      x, nullptr, out);
}